// Round 1
// baseline (56.334 us; speedup 1.0000x reference)
//
#include <hip/hip_runtime.h>
#include <hip/hip_bf16.h>
#include <math.h>

#define BB 8
#define SS 2048
#define HH 768
#define NN 512
#define MAXW 30

// One block (256 threads) per span.
__global__ __launch_bounds__(256) void span_repr_kernel(
    const float* __restrict__ emb,      // (B, S, H)
    const float* __restrict__ w,        // (H, 1)
    const float* __restrict__ bias,     // (1,)
    const int*   __restrict__ starts,   // (B, N)
    const int*   __restrict__ lengths,  // (B, N)
    float*       __restrict__ out)      // (B, N, 3H)
{
    const int span = blockIdx.x;            // 0 .. B*N-1
    const int bi   = span >> 9;             // span / N  (N=512)
    const int tid  = threadIdx.x;

    const int start = starts[span];
    const int len   = lengths[span];        // valid tokens: t = 0..len (inclusive), len <= MAXW-1

    const float* ebase = emb + (size_t)bi * SS * HH;

    __shared__ float s_w[HH];
    __shared__ float s_scores[MAXW];
    __shared__ float s_p[MAXW];

    // Stage w into LDS (768 floats, 3 per thread)
    #pragma unroll
    for (int k = 0; k < 3; ++k) s_w[tid + k * 256] = w[tid + k * 256];
    __syncthreads();

    // ---- Phase A: scores[t] = dot(emb[start+t], w) + b for valid t ----
    // 32 groups of 8 lanes; group g owns token g. Only valid tokens read.
    {
        const int g  = tid >> 3;   // 0..31
        const int lg = tid & 7;    // 0..7
        if (g <= len) {            // len <= 29 < 32
            const float* row = ebase + (size_t)(start + g) * HH;
            float acc = 0.f;
            #pragma unroll
            for (int j = 0; j < 24; ++j) {
                const int h = (lg + j * 8) * 4;      // float4 index coverage of 768
                float4 e4 = *reinterpret_cast<const float4*>(row + h);
                float4 w4 = *reinterpret_cast<const float4*>(s_w + h);
                acc += e4.x * w4.x + e4.y * w4.y + e4.z * w4.z + e4.w * w4.w;
            }
            // reduce across the 8 contiguous lanes of this group
            acc += __shfl_xor(acc, 1);
            acc += __shfl_xor(acc, 2);
            acc += __shfl_xor(acc, 4);
            if (lg == 0) s_scores[g] = acc + bias[0];
        }
    }
    __syncthreads();

    // ---- Phase B: masked softmax over span width (first wave only) ----
    if (tid < 64) {
        const bool valid = (tid <= len) && (tid < MAXW);
        float s = valid ? s_scores[tid] : -INFINITY;
        float m = s;
        #pragma unroll
        for (int off = 32; off; off >>= 1) m = fmaxf(m, __shfl_xor(m, off));
        float e = valid ? __expf(s - m) : 0.f;
        float sum = e;
        #pragma unroll
        for (int off = 32; off; off >>= 1) sum += __shfl_xor(sum, off);
        if (tid < MAXW) s_p[tid] = e / sum;
    }
    __syncthreads();

    // ---- Phase C: outputs. 192 lanes, float4 each (192*4 = 768) ----
    if (tid < HH / 4) {
        const int h = tid * 4;
        float* orow = out + (size_t)span * (3 * HH);

        const float* srow = ebase + (size_t)start * HH;
        const float* erow = ebase + (size_t)(start + len) * HH;
        float4 se = *reinterpret_cast<const float4*>(srow + h);
        float4 ee = *reinterpret_cast<const float4*>(erow + h);
        *reinterpret_cast<float4*>(orow + h)      = se;
        *reinterpret_cast<float4*>(orow + HH + h) = ee;

        float4 acc = make_float4(0.f, 0.f, 0.f, 0.f);
        for (int t = 0; t <= len; ++t) {
            const float p = s_p[t];
            float4 e4 = *reinterpret_cast<const float4*>(ebase + (size_t)(start + t) * HH + h);
            acc.x += p * e4.x;
            acc.y += p * e4.y;
            acc.z += p * e4.z;
            acc.w += p * e4.w;
        }
        *reinterpret_cast<float4*>(orow + 2 * HH + h) = acc;
    }
}

extern "C" void kernel_launch(void* const* d_in, const int* in_sizes, int n_in,
                              void* d_out, int out_size, void* d_ws, size_t ws_size,
                              hipStream_t stream) {
    const float* emb     = (const float*)d_in[0];
    const float* w       = (const float*)d_in[1];
    const float* bias    = (const float*)d_in[2];
    const int*   starts  = (const int*)d_in[3];
    const int*   lengths = (const int*)d_in[4];
    float*       out     = (float*)d_out;

    span_repr_kernel<<<dim3(BB * NN), dim3(256), 0, stream>>>(
        emb, w, bias, starts, lengths, out);
}

// Round 2
// 35.228 us; speedup vs baseline: 1.5991x; 1.5991x over previous
//
#include <hip/hip_runtime.h>
#include <hip/hip_bf16.h>
#include <math.h>

#define BB 8
#define SS 2048
#define HH 768
#define NN 512
#define MAXW 30

// ---- Kernel A: per-example counting sort of spans by start ----
// One block per example, 256 threads. order[b*NN + rank] = span index n.
__global__ __launch_bounds__(256) void sort_spans_kernel(
    const int* __restrict__ starts,   // (B, N)
    int*       __restrict__ order)    // (B, N)
{
    const int b   = blockIdx.x;
    const int tid = threadIdx.x;
    __shared__ int hist[SS];        // 2048 bins
    __shared__ int partial[256];

    for (int i = tid; i < SS; i += 256) hist[i] = 0;
    __syncthreads();

    const int* st = starts + b * NN;
    for (int n = tid; n < NN; n += 256) atomicAdd(&hist[st[n]], 1);
    __syncthreads();

    // chunk sums (8 bins per thread)
    const int base = tid * 8;
    int s = 0;
    #pragma unroll
    for (int k = 0; k < 8; ++k) s += hist[base + k];
    partial[tid] = s;
    __syncthreads();

    if (tid == 0) {           // exclusive scan of 256 partials (tiny kernel, fine)
        int acc = 0;
        for (int i = 0; i < 256; ++i) { int v = partial[i]; partial[i] = acc; acc += v; }
    }
    __syncthreads();

    int acc = partial[tid];   // exclusive scan within chunk
    #pragma unroll
    for (int k = 0; k < 8; ++k) { int v = hist[base + k]; hist[base + k] = acc; acc += v; }
    __syncthreads();

    for (int n = tid; n < NN; n += 256) {
        int pos = atomicAdd(&hist[st[n]], 1);
        order[b * NN + pos] = n;
    }
}

// ---- Kernel B: one block (256 threads) per span, XCD-swizzled sorted order ----
__global__ __launch_bounds__(256) void span_repr_kernel(
    const float* __restrict__ emb,      // (B, S, H)
    const float* __restrict__ w,        // (H, 1)
    const float* __restrict__ bias,     // (1,)
    const int*   __restrict__ starts,   // (B, N)
    const int*   __restrict__ lengths,  // (B, N)
    const int*   __restrict__ order,    // (B, N) or nullptr
    float*       __restrict__ out)      // (B, N, 3H)
{
    // Example b pinned to XCD (blockIdx % 8); rank r sweeps sorted spans.
    const int bi = blockIdx.x & 7;
    const int r  = blockIdx.x >> 3;
    const int n  = order ? order[bi * NN + r] : r;
    const int span = bi * NN + n;
    const int tid  = threadIdx.x;

    const int start = starts[span];
    const int len   = lengths[span];        // valid tokens: t = 0..len (inclusive)

    const float* ebase = emb + (size_t)bi * SS * HH;

    __shared__ float s_w[HH];
    __shared__ float s_scores[MAXW];
    __shared__ float s_p[MAXW];

    #pragma unroll
    for (int k = 0; k < 3; ++k) s_w[tid + k * 256] = w[tid + k * 256];
    __syncthreads();

    // ---- Phase A: scores[t] = dot(emb[start+t], w) + b for valid t ----
    {
        const int g  = tid >> 3;   // 0..31
        const int lg = tid & 7;    // 0..7
        if (g <= len) {            // len <= 29 < 32
            const float* row = ebase + (size_t)(start + g) * HH;
            float acc = 0.f;
            #pragma unroll
            for (int j = 0; j < 24; ++j) {
                const int h = (lg + j * 8) * 4;
                float4 e4 = *reinterpret_cast<const float4*>(row + h);
                float4 w4 = *reinterpret_cast<const float4*>(s_w + h);
                acc += e4.x * w4.x + e4.y * w4.y + e4.z * w4.z + e4.w * w4.w;
            }
            acc += __shfl_xor(acc, 1);
            acc += __shfl_xor(acc, 2);
            acc += __shfl_xor(acc, 4);
            if (lg == 0) s_scores[g] = acc + bias[0];
        }
    }
    __syncthreads();

    // ---- Phase B: masked softmax over span width (first wave only) ----
    if (tid < 64) {
        const bool valid = (tid <= len) && (tid < MAXW);
        float s = valid ? s_scores[tid] : -INFINITY;
        float m = s;
        #pragma unroll
        for (int off = 32; off; off >>= 1) m = fmaxf(m, __shfl_xor(m, off));
        float e = valid ? __expf(s - m) : 0.f;
        float sum = e;
        #pragma unroll
        for (int off = 32; off; off >>= 1) sum += __shfl_xor(sum, off);
        if (tid < MAXW) s_p[tid] = e / sum;
    }
    __syncthreads();

    // ---- Phase C: single pass — weighted sum + start/end rows fused ----
    if (tid < HH / 4) {
        const int h = tid * 4;
        float* orow = out + (size_t)span * (3 * HH);

        float4 acc = make_float4(0.f, 0.f, 0.f, 0.f);
        for (int t = 0; t <= len; ++t) {
            float4 e4 = *reinterpret_cast<const float4*>(
                ebase + (size_t)(start + t) * HH + h);
            if (t == 0)   *reinterpret_cast<float4*>(orow + h)      = e4;  // start row
            if (t == len) *reinterpret_cast<float4*>(orow + HH + h) = e4;  // end row
            const float p = s_p[t];
            acc.x += p * e4.x;
            acc.y += p * e4.y;
            acc.z += p * e4.z;
            acc.w += p * e4.w;
        }
        *reinterpret_cast<float4*>(orow + 2 * HH + h) = acc;
    }
}

extern "C" void kernel_launch(void* const* d_in, const int* in_sizes, int n_in,
                              void* d_out, int out_size, void* d_ws, size_t ws_size,
                              hipStream_t stream) {
    const float* emb     = (const float*)d_in[0];
    const float* w       = (const float*)d_in[1];
    const float* bias    = (const float*)d_in[2];
    const int*   starts  = (const int*)d_in[3];
    const int*   lengths = (const int*)d_in[4];
    float*       out     = (float*)d_out;

    int* order = nullptr;
    if (ws_size >= (size_t)(BB * NN * sizeof(int))) {
        order = (int*)d_ws;
        sort_spans_kernel<<<dim3(BB), dim3(256), 0, stream>>>(starts, order);
    }

    span_repr_kernel<<<dim3(BB * NN), dim3(256), 0, stream>>>(
        emb, w, bias, starts, lengths, order, out);
}